// Round 12
// baseline (8838.341 us; speedup 1.0000x reference)
//
#include <hip/hip_runtime.h>
#include <stdint.h>

#define BB 512
#define TT 512
#define FF 128
#define UU 256

typedef float f32x4 __attribute__((ext_vector_type(4)));
typedef short short8 __attribute__((ext_vector_type(8)));
typedef float float4v __attribute__((ext_vector_type(4)));
typedef unsigned short ushort4v __attribute__((ext_vector_type(4)));

__device__ __forceinline__ unsigned short f2bf(float f) {
  union { float f; uint32_t u; } v; v.f = f;
  uint32_t u = v.u;
  u += 0x7fffu + ((u >> 16) & 1u);
  return (unsigned short)(u >> 16);
}
__device__ __forceinline__ float fast_rcp(float x) { return __builtin_amdgcn_rcpf(x); }
__device__ __forceinline__ float sigmoidf_(float x) { return fast_rcp(1.f + __expf(-x)); }
__device__ __forceinline__ float tanhf_(float x) { return 1.f - 2.f * fast_rcp(1.f + __expf(2.f * x)); }

// ---- prep: Wstrm = per-lane MFMA B-fragments [64 ct][12 kf][64 lanes][8 bf16] ----------
// ct covers the 1024 gate-cols (col = ct*16 + lr); kf covers K=384 (0..3 = x, 4..11 = h).
// Also Wo^T [32][256] bf16 for the fused y GEMM.
__global__ void prep_w(const float* __restrict__ Wx, const float* __restrict__ Wh,
                       const float* __restrict__ Wo,
                       unsigned short* __restrict__ Wstrm, unsigned short* __restrict__ Wot) {
  int bidx = blockIdx.x;
  int tid = threadIdx.x;  // 512
  if (bidx < 768) {
    int ct = bidx / 12, kf = bidx % 12;
    int l = tid >> 3, j = tid & 7;
    int n = ct * 16 + (l & 15);
    int k = kf * 32 + 8 * (l >> 4) + j;
    float v = (k < FF) ? Wx[(size_t)k * 1024 + n] : Wh[(size_t)(k - FF) * 1024 + n];
    Wstrm[((size_t)(ct * 12 + kf) * 64 + l) * 8 + j] = f2bf(v);
  } else {
    for (int i = tid; i < 32 * 256; i += 512) {
      int o = i >> 8, u = i & 255;
      Wot[o * 256 + u] = f2bf(Wo[(size_t)u * 32 + o]);
    }
  }
}

// ---- x f32 -> bf16 ----------------------------------------------------------------------
__global__ void conv_x(const float* __restrict__ xf, unsigned short* __restrict__ xb) {
  size_t i = (size_t)blockIdx.x * 1024 + (size_t)threadIdx.x * 4;
  float4v v = *(const float4v*)(xf + i);
  ushort4v o;
  o.x = f2bf(v.x); o.y = f2bf(v.y); o.z = f2bf(v.z); o.w = f2bf(v.w);
  *(ushort4v*)(xb + i) = o;
}

__device__ __forceinline__ short8 load_xfrag(const unsigned short* p) {
  return *(const short8*)p;
}
__device__ __forceinline__ short8 load_xfrag(const float* p) {
  float4v lo = *(const float4v*)p;
  float4v hi = *(const float4v*)(p + 4);
  union { short8 v; unsigned short s[8]; } a;
  a.s[0] = f2bf(lo.x); a.s[1] = f2bf(lo.y); a.s[2] = f2bf(lo.z); a.s[3] = f2bf(lo.w);
  a.s[4] = f2bf(hi.x); a.s[5] = f2bf(hi.y); a.s[6] = f2bf(hi.z); a.s[7] = f2bf(hi.w);
  return a.v;
}

// ---- local recurrent core: 32 blocks, one block = one m-tile (16 rows x 256 units) ------
// NO inter-block communication. Weights streamed from (XCD-local) L2 every step.
// Wave w owns gate-cols {g*256 + w*32 + c*16 : g in 0..4, c in 0..2} -> 8 col-tiles.
// LDS: [0,16K) h double buffer [2][16 rows][256 units] bf16 XOR-swizzled; [16K,32K) Wo frags.
template <typename XT>
__global__ void __launch_bounds__(512, 2)
lstm_local(const XT* __restrict__ x, const unsigned short* __restrict__ Wstrm,
           const unsigned short* __restrict__ Wot, const float* __restrict__ bvec,
           const float* __restrict__ bo, float* __restrict__ out) {
  __shared__ __align__(16) char lds[32768];
  char* wo_lds = lds + 16384;

  const int bid = blockIdx.x;   // m-tile 0..31
  const int tid = threadIdx.x;
  const int w = tid >> 6, l = tid & 63;
  const int lr = l & 15, lhi = l >> 4;
  const int b0 = bid * 16;

  // stage Wo fragments (waves 0,1; ct = w covers y-cols w*16..w*16+16)
  if (w < 2) {
#pragma unroll
    for (int kf = 0; kf < 8; ++kf) {
      const unsigned short* src = Wot + (size_t)(w * 16 + lr) * 256 + kf * 32 + 8 * lhi;
      *(short8*)(wo_lds + (size_t)((w * 8 + kf) * 64 + l) * 16) = *(const short8*)src;
    }
  }

  float bias_[4][2];
#pragma unroll
  for (int g = 0; g < 4; ++g)
#pragma unroll
    for (int c = 0; c < 2; ++c) bias_[g][c] = bvec[g * 256 + w * 32 + c * 16 + lr];
  const float bob = (w < 2) ? bo[w * 16 + lr] : 0.f;
  float cst[2][4] = {{0.f, 0.f, 0.f, 0.f}, {0.f, 0.f, 0.f, 0.f}};

  // per-lane weight-stream base; frag(q,kf) offset is compile-time after unroll:
  // ct(q) = (q>>1)*16 + w*2 + (q&1);  dword-block idx = ct*12 + kf = w*24 + (q>>1)*192 + (q&1)*12 + kf
  const unsigned short* wb = Wstrm + (size_t)(w * 24) * 512 + (size_t)l * 8;
#define WFRAG(q, kf) (*(const short8*)(wb + (size_t)((((q) >> 1) * 192 + ((q) & 1) * 12 + (kf)) * 512)))

  // prologue x prefetch (t=0)
  short8 xa[4];
  {
    const XT* xp = x + ((size_t)(b0 + lr) * TT + 0) * FF + 8 * lhi;
#pragma unroll
    for (int kk = 0; kk < 4; ++kk) xa[kk] = load_xfrag(xp + kk * 32);
  }
  __syncthreads();  // Wo staging complete

#pragma unroll 1
  for (int t = 0; t < TT; ++t) {
    const int cur = t & 1, nxt = cur ^ 1;

    // issue the first two col-tiles' weight streams
    short8 bE[12], bO[12];
#pragma unroll
    for (int kf = 0; kf < 12; ++kf) bE[kf] = WFRAG(0, kf);
#pragma unroll
    for (int kf = 0; kf < 12; ++kf) bO[kf] = WFRAG(1, kf);

    // h(t) A-fragments from LDS + fused y(t-1) on waves 0,1 (reuses ha)
    short8 ha[8];
    f32x4 yacc = {bob, bob, bob, bob};
    if (t > 0) {
#pragma unroll
      for (int kf = 0; kf < 8; ++kf) {
        const int byte = cur * 8192 + lr * 512 + (((8 * lhi + kf * 32) * 2) ^ ((lr & 7) << 4));
        ha[kf] = *(const short8*)(lds + byte);
      }
      if (w < 2) {
#pragma unroll
        for (int kf = 0; kf < 8; ++kf) {
          short8 wo = *(const short8*)(wo_lds + (size_t)((w * 8 + kf) * 64 + l) * 16);
          yacc = __builtin_amdgcn_mfma_f32_16x16x32_bf16(ha[kf], wo, yacc, 0, 0, 0);
        }
      }
    }

    f32x4 acc[4][2];
#pragma unroll
    for (int g = 0; g < 4; ++g)
#pragma unroll
      for (int c = 0; c < 2; ++c) {
        f32x4 a4 = {bias_[g][c], bias_[g][c], bias_[g][c], bias_[g][c]};
        acc[g][c] = a4;
      }

    // main gate GEMM: 8 col-tiles, even/odd double-buffered weight stream
#pragma unroll
    for (int qq = 0; qq < 4; ++qq) {
      // even tile q=2*qq (c=0)
#pragma unroll
      for (int kf = 0; kf < 4; ++kf)
        acc[qq][0] = __builtin_amdgcn_mfma_f32_16x16x32_bf16(xa[kf], bE[kf], acc[qq][0], 0, 0, 0);
      if (t > 0) {
#pragma unroll
        for (int kf = 0; kf < 8; ++kf)
          acc[qq][0] = __builtin_amdgcn_mfma_f32_16x16x32_bf16(ha[kf], bE[4 + kf], acc[qq][0], 0, 0, 0);
      }
      if (qq < 3) {
#pragma unroll
        for (int kf = 0; kf < 12; ++kf) bE[kf] = WFRAG(2 * qq + 2, kf);
      }
      // odd tile q=2*qq+1 (c=1)
#pragma unroll
      for (int kf = 0; kf < 4; ++kf)
        acc[qq][1] = __builtin_amdgcn_mfma_f32_16x16x32_bf16(xa[kf], bO[kf], acc[qq][1], 0, 0, 0);
      if (t > 0) {
#pragma unroll
        for (int kf = 0; kf < 8; ++kf)
          acc[qq][1] = __builtin_amdgcn_mfma_f32_16x16x32_bf16(ha[kf], bO[4 + kf], acc[qq][1], 0, 0, 0);
      }
      if (qq < 3) {
#pragma unroll
        for (int kf = 0; kf < 12; ++kf) bO[kf] = WFRAG(2 * qq + 3, kf);
      }
    }

    // y(t-1) store (off critical path)
    if (t > 0 && w < 2) {
#pragma unroll
      for (int r = 0; r < 4; ++r)
        out[((size_t)(b0 + 4 * lhi + r) * TT + (t - 1)) * 32 + w * 16 + lr] = yacc[r];
    }

    // x prefetch for t+1
    {
      const int tn = (t + 1 < TT) ? t + 1 : t;
      const XT* xp = x + ((size_t)(b0 + lr) * TT + tn) * FF + 8 * lhi;
#pragma unroll
      for (int kk = 0; kk < 4; ++kk) xa[kk] = load_xfrag(xp + kk * 32);
    }

    // gates: thread holds i,f,g,o for rows b0+4*lhi+r, units w*32 + c*16 + lr
#pragma unroll
    for (int c = 0; c < 2; ++c) {
#pragma unroll
      for (int r = 0; r < 4; ++r) {
        float zi = acc[0][c][r], zf = acc[1][c][r], zg = acc[2][c][r], zo = acc[3][c][r];
        float si = sigmoidf_(zi), sf = sigmoidf_(zf), so = sigmoidf_(zo);
        float tg = tanhf_(zg);
        float cn = sf * cst[c][r] + si * tg;
        cst[c][r] = cn;
        unsigned short hv = f2bf(so * tanhf_(cn));
        const int row = 4 * lhi + r;
        const int unit = w * 32 + c * 16 + lr;
        const int byte = nxt * 8192 + row * 512 + ((unit * 2) ^ ((row & 7) << 4));
        *(unsigned short*)(lds + byte) = hv;
      }
    }

    __syncthreads();  // h(t+1) LDS buffer complete
  }

  // epilogue: y(TT-1) from h(TT) (slot 0, since t=511 wrote nxt=0)
  if (w < 2) {
    f32x4 yacc = {bob, bob, bob, bob};
#pragma unroll
    for (int kf = 0; kf < 8; ++kf) {
      const int byte = 0 * 8192 + lr * 512 + (((8 * lhi + kf * 32) * 2) ^ ((lr & 7) << 4));
      short8 haf = *(const short8*)(lds + byte);
      short8 wo = *(const short8*)(wo_lds + (size_t)((w * 8 + kf) * 64 + l) * 16);
      yacc = __builtin_amdgcn_mfma_f32_16x16x32_bf16(haf, wo, yacc, 0, 0, 0);
    }
#pragma unroll
    for (int r = 0; r < 4; ++r)
      out[((size_t)(b0 + 4 * lhi + r) * TT + (TT - 1)) * 32 + w * 16 + lr] = yacc[r];
  }
#undef WFRAG
}

extern "C" void kernel_launch(void* const* d_in, const int* in_sizes, int n_in,
                              void* d_out, int out_size, void* d_ws, size_t ws_size,
                              hipStream_t stream) {
  const float* x  = (const float*)d_in[0];
  const float* Wx = (const float*)d_in[1];
  const float* Wh = (const float*)d_in[2];
  const float* bv = (const float*)d_in[3];
  const float* Wo = (const float*)d_in[4];
  const float* bo = (const float*)d_in[5];

  char* ws = (char*)d_ws;
  size_t off = 0;
  unsigned short* Wstrm = (unsigned short*)(ws + off); off += (size_t)64 * 12 * 64 * 8 * 2;  // 768 KB
  unsigned short* Wot   = (unsigned short*)(ws + off); off += (size_t)32 * 256 * 2;          // 16 KB
  off = (off + 255) & ~(size_t)255;
  unsigned short* xb = (unsigned short*)(ws + off);
  const size_t need_xb = off + (size_t)BB * TT * FF * 2;  // ~68 MB (ws proven >= 203 MB)

  prep_w<<<769, 512, 0, stream>>>(Wx, Wh, Wo, Wstrm, Wot);
  if (ws_size >= need_xb) {
    conv_x<<<32768, 256, 0, stream>>>(x, xb);
    lstm_local<unsigned short><<<32, 512, 0, stream>>>(xb, Wstrm, Wot, bv, bo, (float*)d_out);
  } else {
    lstm_local<float><<<32, 512, 0, stream>>>(x, Wstrm, Wot, bv, bo, (float*)d_out);
  }
}